// Round 3
// baseline (748.980 us; speedup 1.0000x reference)
//
#include <hip/hip_runtime.h>

// ---------------------------------------------------------------------------
// Attention with log-prob bias + mask, outputs (out, p_attn), fp32 I/O.
// B=2, H=8, N=2048, D=64.  Memory-bound on p/mask reads + p_attn write
// (~800 MB compulsory -> ~127us floor @ 6.3 TB/s).  bf16 MFMA for QK^T and PV.
// R2: 512-thr blocks, fp16-packed chunk-relative exp scores (32 VGPRs),
//     launch_bounds(512,4) -> 16 waves/CU, prefetch pipeline, coalesced prep_vt.
// R3: fix cvt_pkrtz return type (__fp16 vector, not _Float16 vector).
// ---------------------------------------------------------------------------

typedef float  f4v   __attribute__((ext_vector_type(4)));
typedef float  f2v   __attribute__((ext_vector_type(2)));
typedef int    i4v   __attribute__((ext_vector_type(4)));
typedef __bf16 bf16x8 __attribute__((ext_vector_type(8)));
typedef unsigned short us8 __attribute__((ext_vector_type(8)));
typedef unsigned short us4 __attribute__((ext_vector_type(4)));
typedef unsigned int   u4v __attribute__((ext_vector_type(4)));
typedef __fp16 h2v  __attribute__((ext_vector_type(2)));   // matches cvt_pkrtz return

#define MFMA16(a,b,c) __builtin_amdgcn_mfma_f32_16x16x32_bf16((a),(b),(c),0,0,0)

static __device__ __forceinline__ unsigned short f2bf(float f){
  unsigned u = __builtin_bit_cast(unsigned, f);
  u += 0x7fffu + ((u >> 16) & 1u);          // RNE to bf16 (inputs are finite)
  return (unsigned short)(u >> 16);
}
static __device__ __forceinline__ bf16x8 bc8(u4v v){
  return __builtin_bit_cast(bf16x8, v);
}
static __device__ __forceinline__ bf16x8 ldg8(const unsigned short* p){
  u4v v = *(const u4v*)p;                    // 16B aligned by construction
  return __builtin_bit_cast(bf16x8, v);
}

// ---- prep: Q*0.125 and K to bf16 (row-major, same layout as fp32 source) ---
__global__ void prep_qk(const float* __restrict__ Q, const float* __restrict__ K,
                        unsigned short* __restrict__ Qb, unsigned short* __restrict__ Kb){
  int i = blockIdx.x * 256 + threadIdx.x;
  int base = i * 4;
  f4v q = *(const f4v*)(Q + base);
  f4v k = *(const f4v*)(K + base);
  us4 qo, ko;
#pragma unroll
  for(int j=0;j<4;j++){ qo[j] = f2bf(q[j] * 0.125f); ko[j] = f2bf(k[j]); }
  *(us4*)(Qb + base) = qo;
  *(us4*)(Kb + base) = ko;
}

// ---- prep: V -> bf16 transposed Vt[bh][d][n] via coalesced LDS transpose ---
__global__ void prep_vt(const float* __restrict__ V, unsigned short* __restrict__ Vt){
  __shared__ float tile[64*65];
  const int bh = blockIdx.x >> 5;
  const int n0 = (blockIdx.x & 31) << 6;
  const int t  = threadIdx.x;
  {
    const int r  = t >> 2;               // n-row within tile, 0..63
    const int c0 = (t & 3) << 4;         // d-col start 0/16/32/48
    const float* src = V + ((long)bh*2048 + n0 + r)*64 + c0;
    f4v v0 = *(const f4v*)(src);
    f4v v1 = *(const f4v*)(src + 4);
    f4v v2 = *(const f4v*)(src + 8);
    f4v v3 = *(const f4v*)(src + 12);
    float* d = tile + r*65 + c0;
#pragma unroll
    for(int j=0;j<4;j++){ d[j]=v0[j]; d[4+j]=v1[j]; d[8+j]=v2[j]; d[12+j]=v3[j]; }
  }
  __syncthreads();
  const int d  = t >> 2;                 // d-row 0..63
  const int g0 = (t & 3) << 1;           // two n-groups of 8 per thread
#pragma unroll
  for(int gi=0; gi<2; gi++){
    const int g = g0 + gi;
    us8 o;
#pragma unroll
    for(int j=0;j<8;j++) o[j] = f2bf(tile[(g*8 + j)*65 + d]);
    *(us8*)(Vt + ((long)bh*64 + d)*2048 + n0 + g*8) = o;
  }
}

// ---- main fused kernel -----------------------------------------------------
// block = 512 threads (8 waves). One block: 16 q-rows of one (b,h).
// wave w owns keys [w*256, (w+1)*256) in 8 chunks of 32.
// scores stored as fp16-packed e' = exp(s - m_chunk) (chunk-relative, <=1).
__global__ __launch_bounds__(512, 4) void attn_main(
    const float* __restrict__ P, const int* __restrict__ Mk,
    const unsigned short* __restrict__ Qb, const unsigned short* __restrict__ Kb,
    const unsigned short* __restrict__ Vt,
    float* __restrict__ out_o, float* __restrict__ out_p){

  __shared__ float smem[8*1056];     // per-wave: dbuf 16x32 stage (stride 33) / later O-partials (16x66)
  __shared__ float wredm[8][16];
  __shared__ float wreds[8][16];

  const int tid  = threadIdx.x;
  const int w    = tid >> 6;
  const int lane = tid & 63;
  const int m    = lane & 15;        // A-layout row / C-layout col
  const int q    = lane >> 4;        // quad
  const int bidx = blockIdx.x;
  // XCD-swizzle: bidx%8 -> XCD; heads {2x,2x+1} pinned per XCD for K/V L2 reuse
  const int bh = ((bidx & 7) << 1) | ((bidx >> 3) & 1);
  const int qt = bidx >> 4;
  const int q0 = qt << 4;
  const int wbase = w << 8;          // 256 keys per wave

  const long  rowQ  = (long)bh*2048 + q0 + m;
  const long  pbase = rowQ * 2048;
  const unsigned short* Qrow = Qb + rowQ * 64;
  const bf16x8 qf0 = ldg8(Qrow + q*8);
  const bf16x8 qf1 = ldg8(Qrow + 32 + q*8);
  const unsigned short* Kbh = Kb + ((long)bh << 17);
  const unsigned short* Vbh = Vt + ((long)bh << 17);

  const unsigned short* Kp = Kbh + (long)(wbase + m)*64 + q*8;
  const float* pp = P  + pbase + wbase + q*8;
  const int*   mp = Mk + pbase + wbase + q*8;

  h2v   ereg[8][4];                  // 64 scores as packed fp16 (32 VGPRs)
  float mch[8];                      // per-chunk running max
  float mcur = -3.0e38f, vsum = 0.f;
  float* st0 = smem + w*1056;

  // ---------------- phase A: S = QK^T/8 + log(p+1e-12), mask, online exp ---
  u4v k0A = *(const u4v*)(Kp);
  u4v k1A = *(const u4v*)(Kp + 32);
  u4v k2A = *(const u4v*)(Kp + 1024);
  u4v k3A = *(const u4v*)(Kp + 1024 + 32);
  f4v p0A = *(const f4v*)(pp);
  f4v p1A = *(const f4v*)(pp + 4);
  i4v m0A = *(const i4v*)(mp);
  i4v m1A = *(const i4v*)(mp + 4);

#pragma unroll
  for(int c=0;c<8;c++){
    u4v k0N,k1N,k2N,k3N; f4v p0N,p1N; i4v m0N,m1N;
    if(c < 7){                        // prefetch next chunk
      const unsigned short* Kn = Kp + (c+1)*2048;
      k0N = *(const u4v*)(Kn);
      k1N = *(const u4v*)(Kn + 32);
      k2N = *(const u4v*)(Kn + 1024);
      k3N = *(const u4v*)(Kn + 1024 + 32);
      p0N = *(const f4v*)(pp + (c+1)*32);
      p1N = *(const f4v*)(pp + (c+1)*32 + 4);
      m0N = *(const i4v*)(mp + (c+1)*32);
      m1N = *(const i4v*)(mp + (c+1)*32 + 4);
    }
    f4v acc0 = {0.f,0.f,0.f,0.f}, acc1 = {0.f,0.f,0.f,0.f};
    acc0 = MFMA16(qf0, bc8(k0A), acc0);
    acc0 = MFMA16(qf1, bc8(k1A), acc0);
    acc1 = MFMA16(qf0, bc8(k2A), acc1);
    acc1 = MFMA16(qf1, bc8(k3A), acc1);

    float* st = st0 + (c & 1)*528;    // C->A layout staging (wave-local, no barrier)
#pragma unroll
    for(int r=0;r<4;r++){
      st[(4*q + r)*33 + m]      = acc0[r];
      st[(4*q + r)*33 + 16 + m] = acc1[r];
    }
    float s[8];
#pragma unroll
    for(int j=0;j<8;j++){
      float pj = (j < 4) ? p0A[j] : p1A[j-4];
      int   mj = (j < 4) ? m0A[j] : m1A[j-4];
      float sc = st[m*33 + q*8 + j] + __logf(pj + 1e-12f);
      s[j] = (mj == 0) ? -1.0e9f : sc;
    }
    float cm = s[0];
#pragma unroll
    for(int j=1;j<8;j++) cm = fmaxf(cm, s[j]);
    float mn = fmaxf(mcur, cm);
    vsum *= __expf(mcur - mn);        // rescale old sum (vsum=0 first time)
#pragma unroll
    for(int jj=0;jj<4;jj++){
      float e0 = __expf(s[2*jj]   - mn);
      float e1 = __expf(s[2*jj+1] - mn);
      vsum += e0 + e1;
      ereg[c][jj] = __builtin_amdgcn_cvt_pkrtz(e0, e1);
    }
    mch[c] = mn; mcur = mn;

    k0A=k0N; k1A=k1N; k2A=k2N; k3A=k3N;
    p0A=p0N; p1A=p1N; m0A=m0N; m1A=m1N;
  }

  // ---------------- row (max,sum) reduce: quad shuffles + cross-wave LDS ---
  {
    float om = __shfl_xor(mcur, 16), ov = __shfl_xor(vsum, 16);
    float nm = fmaxf(mcur, om);
    vsum = vsum*__expf(mcur - nm) + ov*__expf(om - nm); mcur = nm;
    om = __shfl_xor(mcur, 32); ov = __shfl_xor(vsum, 32);
    nm = fmaxf(mcur, om);
    vsum = vsum*__expf(mcur - nm) + ov*__expf(om - nm); mcur = nm;
  }
  if(lane < 16){ wredm[w][lane] = mcur; wreds[w][lane] = vsum; }
  __syncthreads();
  float Mrow = -3.0e38f;
#pragma unroll
  for(int p2=0;p2<8;p2++) Mrow = fmaxf(Mrow, wredm[p2][m]);
  float l = 0.f;
#pragma unroll
  for(int p2=0;p2<8;p2++) l += wreds[p2][m]*__expf(wredm[p2][m] - Mrow);
  const float rl = 1.0f / l;

  // ---------------- phase C: write p_attn, O += P*V -------------------------
  f4v o0={0.f,0.f,0.f,0.f}, o1={0.f,0.f,0.f,0.f}, o2={0.f,0.f,0.f,0.f}, o3={0.f,0.f,0.f,0.f};
#pragma unroll
  for(int c=0;c<8;c++){
    const float f = __expf(mch[c] - Mrow) * rl;   // chunk rescale factor
    const int k0 = wbase + c*32;
    f4v w0, w1; us8 pb;
#pragma unroll
    for(int jj=0;jj<4;jj++){
      h2v ee = ereg[c][jj];
      float pr0 = (float)ee[0] * f;
      float pr1 = (float)ee[1] * f;
      if(jj < 2){ w0[2*jj] = pr0; w0[2*jj+1] = pr1; }
      else      { w1[2*jj-4] = pr0; w1[2*jj-3] = pr1; }
      pb[2*jj]   = f2bf(pr0);
      pb[2*jj+1] = f2bf(pr1);
    }
    float* op = out_p + pbase + k0 + q*8;
    *(f4v*)op       = w0;
    *(f4v*)(op + 4) = w1;
    bf16x8 af = __builtin_bit_cast(bf16x8, pb);
    const unsigned short* Vp = Vbh + (long)m*2048 + k0 + q*8;
    o0 = MFMA16(af, ldg8(Vp),           o0);
    o1 = MFMA16(af, ldg8(Vp + 16*2048), o1);
    o2 = MFMA16(af, ldg8(Vp + 32*2048), o2);
    o3 = MFMA16(af, ldg8(Vp + 48*2048), o3);
  }

  // ---------------- O: cross-wave sum + store (reuse stage LDS, stride 66) --
  float* ob = smem + w*1056;          // own plane; stage no longer needed
#pragma unroll
  for(int r=0;r<4;r++){
    ob[(4*q + r)*66 + m]      = o0[r];
    ob[(4*q + r)*66 + 16 + m] = o1[r];
    ob[(4*q + r)*66 + 32 + m] = o2[r];
    ob[(4*q + r)*66 + 48 + m] = o3[r];
  }
  __syncthreads();
  const int row = tid >> 5;           // 16 rows x 32 threads
  const int c2  = (tid & 31) << 1;    // 2 cols per thread
  f2v s2 = {0.f, 0.f};
#pragma unroll
  for(int p2=0;p2<8;p2++){
    f2v a = *(const f2v*)(smem + p2*1056 + row*66 + c2);
    s2 += a;
  }
  *(f2v*)(out_o + ((long)bh*2048 + q0 + row)*64 + c2) = s2;
}

// ---------------------------------------------------------------------------
extern "C" void kernel_launch(void* const* d_in, const int* in_sizes, int n_in,
                              void* d_out, int out_size, void* d_ws, size_t ws_size,
                              hipStream_t stream){
  const float* Q = (const float*)d_in[0];
  const float* K = (const float*)d_in[1];
  const float* V = (const float*)d_in[2];
  const int*   M = (const int*)  d_in[3];
  const float* P = (const float*)d_in[4];

  float* out_o = (float*)d_out;                       // [2,8,2048,64]
  float* out_p = out_o + (size_t)2*8*2048*64;         // [2,8,2048,2048]

  unsigned short* Qb = (unsigned short*)d_ws;         // 4MB
  unsigned short* Kb = Qb + (size_t)2*8*2048*64;      // 4MB
  unsigned short* Vt = Kb + (size_t)2*8*2048*64;      // 4MB (transposed)

  prep_qk<<<2048, 256, 0, stream>>>(Q, K, Qb, Kb);
  prep_vt<<<512, 256, 0, stream>>>(V, Vt);
  attn_main<<<2048, 512, 0, stream>>>(P, M, Qb, Kb, Vt, out_o, out_p);
}